// Round 7
// baseline (648.853 us; speedup 1.0000x reference)
//
#include <hip/hip_runtime.h>
#include <hip/hip_bf16.h>

using bf16 = __hip_bfloat16;
using frag8 = __attribute__((ext_vector_type(8))) short;  // 8 bf16 (4 VGPRs)
using f32x4 = __attribute__((ext_vector_type(4))) float;  // MFMA C/D

__device__ __forceinline__ short f2bf_bits(float f) {
  bf16 h = __float2bfloat16(f);
  short s; __builtin_memcpy(&s, &h, 2); return s;
}
__device__ __forceinline__ float bfbits2f(unsigned short u) {
  unsigned uu = (unsigned)u << 16; float f; __builtin_memcpy(&f, &uu, 4); return f;
}
__device__ __forceinline__ float wred_sum(float v) {
#pragma unroll
  for (int o = 32; o; o >>= 1) v += __shfl_xor(v, o);
  return v;
}

// ---- dtype detector (flag=1 -> fp32 inputs, 0 -> bf16) ----
__global__ void detect_k(const unsigned* __restrict__ x, int* __restrict__ flag) {
  __shared__ int sh[256];
  int tid = threadIdx.x, c = 0;
  for (int i = tid; i < 4096; i += 256) {
    unsigned b = (x[i] >> 8) & 0x7F;
    c += (b >= 0x3B && b <= 0x41) ? 1 : 0;
  }
  sh[tid] = c; __syncthreads();
  for (int off = 128; off; off >>= 1) { if (tid < off) sh[tid] += sh[tid + off]; __syncthreads(); }
  if (tid == 0) flag[0] = (sh[0] < 2048) ? 1 : 0;
}

// ---- canonicalize params. mode 0: -> fp32 copy. mode 1: -> bf16 TRANSPOSE:
// dst[n*Kt+k] = src[k*128+n]. ----
struct ConvJob { const void* src; void* dst; int n; int mode; int ksh; };
struct ConvJobs { ConvJob j[32]; };
__global__ void conv_k(ConvJobs jobs, const int* __restrict__ flagp) {
  const int f = flagp[0];
  ConvJob J = jobs.j[blockIdx.x];
  const int Kt = 1 << J.ksh;
  for (int i = threadIdx.x; i < J.n; i += blockDim.x) {
    int si = i;
    if (J.mode == 1) { int n = i >> J.ksh, k = i & (Kt - 1); si = k * 128 + n; }
    float v = f ? ((const float*)J.src)[si] : bfbits2f(((const unsigned short*)J.src)[si]);
    if (J.mode == 1) ((bf16*)J.dst)[i] = __float2bfloat16(v);
    else             ((float*)J.dst)[i] = v;
  }
}

// ---- wa[k][h] = sum_d W[k][h*D+d] * adv[h*D+d]  (from WT[n][128] bf16) ----
struct WaJob { const bf16* wt; const float* adv; float* out; int H; };
struct WaJobs { WaJob j[4]; };
__global__ void wa_k(WaJobs jobs) {
  WaJob J = jobs.j[blockIdx.x];
  int k = threadIdx.x;
  if (k >= 128) return;
  const int D = 128 / J.H;
  for (int h = 0; h < J.H; h++) {
    float s = 0.f;
    for (int d = 0; d < D; d++) {
      int col = h * D + d;
      s += __bfloat162float(J.wt[col * 128 + k]) * J.adv[col];
    }
    J.out[k * J.H + h] = s;
  }
}

// ---- full GEMM: C[M x 128] = A[M x K] @ W; WT pre-transposed [128][K] bf16.
__global__ __launch_bounds__(256) void gemm_tf(
    const void* __restrict__ Av, int M, int K,
    const bf16* __restrict__ WT,
    const float* __restrict__ bias,
    const float* __restrict__ avec,
    bf16* __restrict__ outFull,
    float* __restrict__ outScore,
    int H,
    const int* __restrict__ flagp)
{
  __shared__ __align__(16) bf16 Wt[128 * 136];
  const int tid = threadIdx.x;
  const int isf32 = flagp ? flagp[0] : 0;
  const int stride = K + 8;
  const int ksh2 = (K == 128) ? 4 : 3;
  const int kunits = K >> 3;
  for (int u = tid; u < 128 * kunits; u += 256) {
    int n = u >> ksh2, kb = u & (kunits - 1);
    frag8 v = *(const frag8*)(WT + n * K + kb * 8);
    *(frag8*)(Wt + n * stride + kb * 8) = v;
  }
  __syncthreads();

  const int lane = tid & 63, wave = tid >> 6;
  const int quad = lane >> 4, c = lane & 15;
  const int mbase = blockIdx.x * 64 + wave * 16;
  const int arow = mbase + c;
  const bool rowOK = arow < M;

  f32x4 acc[8];
#pragma unroll
  for (int t = 0; t < 8; t++) acc[t] = (f32x4){0.f, 0.f, 0.f, 0.f};

  for (int ks = 0; ks < K; ks += 32) {
    frag8 af;
    const int k0 = ks + quad * 8;
    if (rowOK) {
      if (isf32) {
        const float* ap = (const float*)Av + (size_t)arow * K + k0;
#pragma unroll
        for (int j = 0; j < 8; j++) af[j] = f2bf_bits(ap[j]);
      } else {
        af = *(const frag8*)((const bf16*)Av + (size_t)arow * K + k0);
      }
    } else {
#pragma unroll
      for (int j = 0; j < 8; j++) af[j] = 0;
    }
#pragma unroll
    for (int t = 0; t < 8; t++) {
      frag8 bfv = *(const frag8*)(Wt + (t * 16 + c) * stride + k0);
      acc[t] = __builtin_amdgcn_mfma_f32_16x16x32_bf16(af, bfv, acc[t], 0, 0, 0);
    }
  }

  if (outFull) {
#pragma unroll
    for (int t = 0; t < 8; t++) {
#pragma unroll
      for (int r = 0; r < 4; r++) {
        int orow = mbase + quad * 4 + r;
        if (orow < M) {
          float v = acc[t][r];
          if (bias) v += bias[t * 16 + c];
          outFull[(size_t)orow * 128 + t * 16 + c] = __float2bfloat16(v);
        }
      }
    }
  }
  if (outScore) {
    const int TPH = 8 / H;
    for (int hh = 0; hh < H; hh++) {
#pragma unroll
      for (int r = 0; r < 4; r++) {
        float p = 0.f;
        for (int tt = 0; tt < TPH; tt++) {
          int t = hh * TPH + tt;
          p += acc[t][r] * avec[t * 16 + c];
        }
#pragma unroll
        for (int off = 1; off < 16; off <<= 1) p += __shfl_xor(p, off);
        int orow = mbase + quad * 4 + r;
        if (c == 0 && orow < M) outScore[(size_t)orow * H + hh] = p;
      }
    }
  }
}

// ---- GEMV: ad[n][h] = sum_k hX[n][k] * wa[k][h]. Each lane covers dims
// 2*lane, 2*lane+1 for ALL H heads; full 64-lane reduce per head. ----
template<int H>
__global__ __launch_bounds__(256) void gemv_ad(
    const unsigned* __restrict__ hX, int N,
    const float* __restrict__ wa,      // [128][H]
    float* __restrict__ ad)
{
  const int wave = threadIdx.x >> 6, lane = threadIdx.x & 63;
  float w0[H], w1[H];
#pragma unroll
  for (int h = 0; h < H; h++) {
    w0[h] = wa[(2 * lane) * H + h];
    w1[h] = wa[(2 * lane + 1) * H + h];
  }
  for (int n = blockIdx.x * 4 + wave; n < N; n += gridDim.x * 4) {
    unsigned u = hX[(size_t)n * 64 + lane];
    float x0 = bfbits2f((unsigned short)(u & 0xFFFF));
    float x1 = bfbits2f((unsigned short)(u >> 16));
    float p[H];
#pragma unroll
    for (int h = 0; h < H; h++) p[h] = x0 * w0[h] + x1 * w1[h];
#pragma unroll
    for (int h = 0; h < H; h++) p[h] = wred_sum(p[h]);
    if (lane == 0) {
      if (H == 4) *(float4*)(ad + (size_t)n * 4) = make_float4(p[0], p[1], p[2], p[3 % H]);
      else        ad[n] = p[0];
    }
  }
}

// ---- fused CSR build (both directions per kernel) ----
__global__ void zero2_k(int* a, int na, int* b, int nb) {
  int i = blockIdx.x * 256 + threadIdx.x;
  if (i < na) a[i] = 0;
  else if (i < na + nb) b[i - na] = 0;
}
__global__ void hist2_k(const int* __restrict__ dA, const int* __restrict__ dB, int E,
                        int* __restrict__ cA, int* __restrict__ cB) {
  int i = blockIdx.x * 256 + threadIdx.x;
  if (i < E) atomicAdd(&cA[dA[i]], 1);
  else if (i < 2 * E) atomicAdd(&cB[dB[i - E]], 1);
}
__global__ void blocksum2_k(const int* __restrict__ cA, int nA, int* __restrict__ bsA, int nbA_,
                            const int* __restrict__ cB, int nB, int* __restrict__ bsB) {
  __shared__ int sh[256];
  const int tid = threadIdx.x;
  const int* cnt; int N; int* bsum; int bb;
  if ((int)blockIdx.x < nbA_) { cnt = cA; N = nA; bsum = bsA; bb = blockIdx.x; }
  else { cnt = cB; N = nB; bsum = bsB; bb = blockIdx.x - nbA_; }
  const int beg = bb * 1024;
  const int end = (beg + 1024 < N) ? beg + 1024 : N;
  int loc = 0;
  for (int i = beg + tid; i < end; i += 256) loc += cnt[i];
  sh[tid] = loc; __syncthreads();
  for (int off = 128; off; off >>= 1) { if (tid < off) sh[tid] += sh[tid + off]; __syncthreads(); }
  if (tid == 0) bsum[bb] = sh[0];
}
__global__ void scanpart2_k(int* __restrict__ bsA, int nbA_, int* __restrict__ bsB, int nbB_) {
  __shared__ int sh[256];
  const int tid = threadIdx.x;
  int* bsum; int nb;
  if (blockIdx.x == 0) { bsum = bsA; nb = nbA_; } else { bsum = bsB; nb = nbB_; }
  int v = (tid < nb) ? bsum[tid] : 0;
  sh[tid] = v; __syncthreads();
  for (int off = 1; off < 256; off <<= 1) {
    int x = sh[tid];
    int o = (tid >= off) ? sh[tid - off] : 0;
    __syncthreads();
    sh[tid] = x + o;
    __syncthreads();
  }
  if (tid < nb) bsum[tid] = (tid == 0) ? 0 : sh[tid - 1];
}
__global__ void writerp2_k(const int* __restrict__ cA, int nA, const int* __restrict__ bsA, int nbA_,
                           int* __restrict__ rpA, int* __restrict__ curA,
                           const int* __restrict__ cB, int nB, const int* __restrict__ bsB,
                           int* __restrict__ rpB, int* __restrict__ curB) {
  __shared__ int sh[256];
  const int tid = threadIdx.x;
  const int* cnt; int N; const int* bsum; int* rp; int* cur; int bb;
  if ((int)blockIdx.x < nbA_) { cnt = cA; N = nA; bsum = bsA; rp = rpA; cur = curA; bb = blockIdx.x; }
  else { cnt = cB; N = nB; bsum = bsB; rp = rpB; cur = curB; bb = blockIdx.x - nbA_; }
  const int idx0 = bb * 1024 + tid * 4;
  int c[4]; int loc = 0;
#pragma unroll
  for (int j = 0; j < 4; j++) {
    int i = idx0 + j;
    c[j] = (i < N) ? cnt[i] : 0;
    loc += c[j];
  }
  sh[tid] = loc; __syncthreads();
  for (int off = 1; off < 256; off <<= 1) {
    int x = sh[tid];
    int o = (tid >= off) ? sh[tid - off] : 0;
    __syncthreads();
    sh[tid] = x + o;
    __syncthreads();
  }
  int run = bsum[bb] + ((tid == 0) ? 0 : sh[tid - 1]);
#pragma unroll
  for (int j = 0; j < 4; j++) {
    int i = idx0 + j;
    if (i < N) { rp[i] = run; cur[i] = run; }
    run += c[j];
  }
  if (idx0 <= N - 1 && N - 1 < idx0 + 4) rp[N] = run;
}
__global__ void scatter2_k(const int* __restrict__ sA, const int* __restrict__ dA,
                           int* __restrict__ curA, int* __restrict__ slA, int* __restrict__ dlA,
                           const int* __restrict__ sB, const int* __restrict__ dB,
                           int* __restrict__ curB, int* __restrict__ slB, int* __restrict__ dlB,
                           int E) {
  int i = blockIdx.x * 256 + threadIdx.x;
  if (i < E) {
    int d = dA[i];
    int pos = atomicAdd(&curA[d], 1);
    slA[pos] = sA[i]; dlA[pos] = d;
  } else if (i < 2 * E) {
    int ii = i - E;
    int d = dB[ii];
    int pos = atomicAdd(&curB[d], 1);
    slB[pos] = sB[ii]; dlB[pos] = d;
  }
}

// ---- edge weights, both directions in one launch ----
template<int H>
__global__ void edgep2_k(
    const int* __restrict__ slA, const int* __restrict__ dlA,
    const float* __restrict__ asA, const float* __restrict__ adA, float* __restrict__ pA,
    const int* __restrict__ slB, const int* __restrict__ dlB,
    const float* __restrict__ asB, const float* __restrict__ adB, float* __restrict__ pB,
    int E)
{
  int i = blockIdx.x * 256 + threadIdx.x;
  if (i >= 2 * E) return;
  const int* sl; const int* dl; const float* as_; const float* ad_; float* p; int e;
  if (i < E) { sl = slA; dl = dlA; as_ = asA; ad_ = adA; p = pA; e = i; }
  else { sl = slB; dl = dlB; as_ = asB; ad_ = adB; p = pB; e = i - E; }
  int s = sl[e], d = dl[e];
  if (H == 4) {
    float4 a = *(const float4*)(as_ + (size_t)s * 4);
    float4 b = *(const float4*)(ad_ + (size_t)d * 4);
    float4 o; float v;
    v = a.x + b.x; v = v > 0.f ? v : 0.2f * v; o.x = __expf(v);
    v = a.y + b.y; v = v > 0.f ? v : 0.2f * v; o.y = __expf(v);
    v = a.z + b.z; v = v > 0.f ? v : 0.2f * v; o.z = __expf(v);
    v = a.w + b.w; v = v > 0.f ? v : 0.2f * v; o.w = __expf(v);
    *(float4*)(p + (size_t)e * 4) = o;
  } else {
    float v = as_[s] + ad_[d];
    v = v > 0.f ? v : 0.2f * v;
    p[e] = __expf(v);
  }
}

// ---- GAT aggregate v4: wave per node; 8-deep pipelined hs gather (src via
// __shfl, p via LDS); then bias+LN+ReLU+resid epilogue. ----
template<int H, bool FINAL>
__global__ __launch_bounds__(256) void gat_agg(
    const int* __restrict__ rp,
    const int* __restrict__ srcl,
    const float* __restrict__ pbuf,
    const bf16* __restrict__ hs,
    const float* __restrict__ bias,
    const float* __restrict__ gamma,
    const float* __restrict__ beta,
    const bf16* __restrict__ resid,
    bf16* __restrict__ outBf,
    void* __restrict__ outFinal,
    int nodeBase,
    const int* __restrict__ flagp,
    int N)
{
  __shared__ float s_p[4][64 * H];
  const int wave = threadIdx.x >> 6, lane = threadIdx.x & 63;
  const int n = blockIdx.x * 4 + wave;
  if (n >= N) return;

  const int beg = rp[n], end = rp[n + 1];
  const int myh = (H == 4) ? (lane >> 4) : 0;
  float sl_[H];
#pragma unroll
  for (int h = 0; h < H; h++) sl_[h] = 0.f;
  float acc0 = 0.f, acc1 = 0.f;
  const unsigned* hsu = (const unsigned*)hs;

  for (int base = beg; base < end; base += 64) {
    const int cn = min(64, end - base);
    int esrc = 0;
    if (lane < cn) {
      esrc = srcl[base + lane];
      if (H == 4) {
        float4 pv = *(const float4*)(pbuf + (size_t)(base + lane) * 4);
        *(float4*)&s_p[wave][lane * 4] = pv;
        sl_[0] += pv.x; sl_[1] += pv.y; sl_[2] += pv.z; sl_[3] += pv.w;
      } else {
        float pv = pbuf[base + lane];
        s_p[wave][lane] = pv;
        sl_[0] += pv;
      }
    }
    __builtin_amdgcn_wave_barrier();
    for (int e0 = 0; e0 < cn; e0 += 8) {
      unsigned u[8]; float pp[8];
#pragma unroll
      for (int j = 0; j < 8; j++) {
        int e = e0 + j;
        int ec = e < cn ? e : cn - 1;          // clamped: address always valid
        int s = __shfl(esrc, ec);
        u[j] = hsu[(size_t)s * 64 + lane];
        pp[j] = (e < cn) ? s_p[wave][ec * H + myh] : 0.f;
      }
#pragma unroll
      for (int j = 0; j < 8; j++) {
        acc0 += pp[j] * bfbits2f((unsigned short)(u[j] & 0xFFFF));
        acc1 += pp[j] * bfbits2f((unsigned short)(u[j] >> 16));
      }
    }
    __builtin_amdgcn_wave_barrier();
  }

  float s = 0.f;
#pragma unroll
  for (int h = 0; h < H; h++) {
    float t = wred_sum(sl_[h]);
    if (h == myh) s = t;
  }
  const float inv = 1.f / (s + 1e-16f);
  float2 bi = *(const float2*)(bias + 2 * lane);
  float y0 = acc0 * inv + bi.x;
  float y1 = acc1 * inv + bi.y;

  float tsum = wred_sum(y0 + y1);
  float tsq  = wred_sum(y0 * y0 + y1 * y1);
  float mu = tsum * 0.0078125f;
  float var = tsq * 0.0078125f - mu * mu;
  float rs = rsqrtf(var + 1e-5f);
  float2 ga = *(const float2*)(gamma + 2 * lane);
  float2 be = *(const float2*)(beta + 2 * lane);
  float z0 = (y0 - mu) * rs * ga.x + be.x;
  float z1 = (y1 - mu) * rs * ga.y + be.y;
  unsigned ru = *(const unsigned*)(resid + (size_t)n * 128 + 2 * lane);
  z0 = fmaxf(z0, 0.f) + bfbits2f((unsigned short)(ru & 0xFFFF));
  z1 = fmaxf(z1, 0.f) + bfbits2f((unsigned short)(ru >> 16));

  if constexpr (FINAL) {
    size_t oi = (size_t)(nodeBase + n) * 128 + 2 * lane;
    if (flagp[0]) {
      *(float2*)((float*)outFinal + oi) = make_float2(z0, z1);
    } else {
      unsigned short l0 = (unsigned short)f2bf_bits(z0);
      unsigned short l1 = (unsigned short)f2bf_bits(z1);
      *(unsigned*)((bf16*)outFinal + oi) = (unsigned)l0 | ((unsigned)l1 << 16);
    }
  } else {
    unsigned short l0 = (unsigned short)f2bf_bits(z0);
    unsigned short l1 = (unsigned short)f2bf_bits(z1);
    *(unsigned*)(outBf + (size_t)n * 128 + 2 * lane) = (unsigned)l0 | ((unsigned)l1 << 16);
  }
}

extern "C" void kernel_launch(void* const* d_in, const int* in_sizes, int n_in,
                              void* d_out, int out_size, void* d_ws, size_t ws_size,
                              hipStream_t stream)
{
  const int NA = in_sizes[0] / 128;
  const int NB = in_sizes[1] / 64;
  const int E  = in_sizes[30] / 2;
  const int* eiAB = (const int*)d_in[30];
  const int* eiBA = (const int*)d_in[31];
  const int* srcAB = eiAB;  const int* dstAB = eiAB + E;
  const int* srcBA = eiBA;  const int* dstBA = eiBA + E;

  char* w = (char*)d_ws;
  size_t used = 0;
  auto alloc = [&](size_t bytes) {
    char* p = w + used;
    used += (bytes + 255) & ~size_t(255);
    return (void*)p;
  };
  int*  flag  = (int*)alloc(256);
  bf16* WcA   = (bf16*)alloc(16384 * 2);
  bf16* WcB   = (bf16*)alloc(8192 * 2);
  bf16* Wc0ab = (bf16*)alloc(16384 * 2);
  bf16* Wc0ba = (bf16*)alloc(16384 * 2);
  bf16* Wc1ab = (bf16*)alloc(16384 * 2);
  bf16* Wc1ba = (bf16*)alloc(16384 * 2);
  float* vec  = (float*)alloc(22 * 128 * 4);
  float* wa0ab = (float*)alloc(128 * 4 * 4);
  float* wa0ba = (float*)alloc(128 * 4 * 4);
  float* wa1ab = (float*)alloc(128 * 4);
  float* wa1ba = (float*)alloc(128 * 4);
  bf16* hA    = (bf16*)alloc((size_t)NA * 128 * 2);
  bf16* hB    = (bf16*)alloc((size_t)NB * 128 * 2);
  bf16* hsAB  = (bf16*)alloc((size_t)NA * 128 * 2);
  bf16* hsBA  = (bf16*)alloc((size_t)NB * 128 * 2);
  float* asAB = (float*)alloc((size_t)NA * 4 * 4);
  float* adAB = (float*)alloc((size_t)NB * 4 * 4);
  float* asBA = (float*)alloc((size_t)NB * 4 * 4);
  float* adBA = (float*)alloc((size_t)NA * 4 * 4);
  int* rpAB = (int*)alloc((size_t)(NB + 1) * 4);
  int* slAB = (int*)alloc((size_t)E * 4);
  int* dlAB = (int*)alloc((size_t)E * 4);
  int* rpBA = (int*)alloc((size_t)(NA + 1) * 4);
  int* slBA = (int*)alloc((size_t)E * 4);
  int* dlBA = (int*)alloc((size_t)E * 4);
  float* pbufAB = (float*)alloc((size_t)E * 4 * 4);
  float* pbufBA = (float*)alloc((size_t)E * 4 * 4);
  int* cntAB = (int*)alloc((size_t)NB * 4);
  int* curAB = (int*)alloc((size_t)NB * 4);
  int* cntBA = (int*)alloc((size_t)NA * 4);
  int* curBA = (int*)alloc((size_t)NA * 4);
  int* bsumAB = (int*)alloc(256 * 4);
  int* bsumBA = (int*)alloc(256 * 4);
  if (used > ws_size) return;

  auto V = [&](int i) { return vec + 128 * i; };
  // vec slots: 0 pbA, 1 pbB, 2 as0ab, 3 ad0ab, 4 b0ab, 5 as0ba, 6 ad0ba,
  // 7 b0ba, 8 as1ab, 9 ad1ab, 10 b1ab, 11 as1ba, 12 ad1ba, 13 b1ba,
  // 14 g0A, 15 bn0A, 16 g0B, 17 bn0B, 18 g1A, 19 bn1A, 20 g1B, 21 bn1B

  detect_k<<<1, 256, 0, stream>>>((const unsigned*)d_in[0], flag);

  ConvJobs jobs{};
  int nj = 0;
  auto addT = [&](const void* s, void* d, int K) {
    int ksh = (K == 128) ? 7 : 6;
    jobs.j[nj++] = ConvJob{s, d, 128 * K, 1, ksh};
  };
  auto addV = [&](const void* s, void* d) { jobs.j[nj++] = ConvJob{s, d, 128, 0, 7}; };
  addT(d_in[2], WcA, 128);
  addT(d_in[4], WcB, 64);
  addT(d_in[6], Wc0ab, 128);
  addT(d_in[10], Wc0ba, 128);
  addT(d_in[14], Wc1ab, 128);
  addT(d_in[18], Wc1ba, 128);
  const int vsrc[22] = {3, 5, 7, 8, 9, 11, 12, 13, 15, 16, 17, 19, 20, 21, 22, 23, 24, 25, 26, 27, 28, 29};
  for (int i = 0; i < 22; i++) addV(d_in[vsrc[i]], V(i));
  conv_k<<<nj, 256, 0, stream>>>(jobs, flag);

  WaJobs wj{};
  wj.j[0] = WaJob{Wc0ab, V(3),  wa0ab, 4};
  wj.j[1] = WaJob{Wc0ba, V(6),  wa0ba, 4};
  wj.j[2] = WaJob{Wc1ab, V(9),  wa1ab, 1};
  wj.j[3] = WaJob{Wc1ba, V(12), wa1ba, 1};
  wa_k<<<4, 128, 0, stream>>>(wj);

  // ---- CSR both directions, fused phases ----
  const int nbB = (NB + 1023) / 1024, nbA = (NA + 1023) / 1024;
  zero2_k<<<(NA + NB + 255) / 256, 256, 0, stream>>>(cntAB, NB, cntBA, NA);
  hist2_k<<<(2 * E + 255) / 256, 256, 0, stream>>>(dstAB, dstBA, E, cntAB, cntBA);
  blocksum2_k<<<nbB + nbA, 256, 0, stream>>>(cntAB, NB, bsumAB, nbB, cntBA, NA, bsumBA);
  scanpart2_k<<<2, 256, 0, stream>>>(bsumAB, nbB, bsumBA, nbA);
  writerp2_k<<<nbB + nbA, 256, 0, stream>>>(cntAB, NB, bsumAB, nbB, rpAB, curAB,
                                            cntBA, NA, bsumBA, rpBA, curBA);
  scatter2_k<<<(2 * E + 255) / 256, 256, 0, stream>>>(srcAB, dstAB, curAB, slAB, dlAB,
                                                      srcBA, dstBA, curBA, slBA, dlBA, E);

  const int gA = (NA + 63) / 64, gB = (NB + 63) / 64;
  const int aA = (NA + 3) / 4, aB = (NB + 3) / 4;
  const int ge2 = (2 * E + 255) / 256;

  // ---- input projections ----
  gemm_tf<<<gA, 256, 0, stream>>>(d_in[0], NA, 128, WcA, V(0), nullptr, hA, nullptr, 1, flag);
  gemm_tf<<<gB, 256, 0, stream>>>(d_in[1], NB, 64,  WcB, V(1), nullptr, hB, nullptr, 1, flag);

  // ---- layer 0 (H=4) ----
  gemm_tf<<<gA, 256, 0, stream>>>(hA, NA, 128, Wc0ab, nullptr, V(2), hsAB, asAB, 4, nullptr);
  gemm_tf<<<gB, 256, 0, stream>>>(hB, NB, 128, Wc0ba, nullptr, V(5), hsBA, asBA, 4, nullptr);
  gemv_ad<4><<<256, 256, 0, stream>>>((const unsigned*)hB, NB, wa0ab, adAB);
  gemv_ad<4><<<256, 256, 0, stream>>>((const unsigned*)hA, NA, wa0ba, adBA);
  edgep2_k<4><<<ge2, 256, 0, stream>>>(slAB, dlAB, asAB, adAB, pbufAB,
                                       slBA, dlBA, asBA, adBA, pbufBA, E);
  gat_agg<4, false><<<aB, 256, 0, stream>>>(rpAB, slAB, pbufAB, hsAB, V(4), V(16), V(17), hB, hB, nullptr, 0, nullptr, NB);
  gat_agg<4, false><<<aA, 256, 0, stream>>>(rpBA, slBA, pbufBA, hsBA, V(7), V(14), V(15), hA, hA, nullptr, 0, nullptr, NA);

  // ---- layer 1 (H=1) ----
  gemm_tf<<<gA, 256, 0, stream>>>(hA, NA, 128, Wc1ab, nullptr, V(8),  hsAB, asAB, 1, nullptr);
  gemm_tf<<<gB, 256, 0, stream>>>(hB, NB, 128, Wc1ba, nullptr, V(11), hsBA, asBA, 1, nullptr);
  gemv_ad<1><<<256, 256, 0, stream>>>((const unsigned*)hB, NB, wa1ab, adAB);
  gemv_ad<1><<<256, 256, 0, stream>>>((const unsigned*)hA, NA, wa1ba, adBA);
  edgep2_k<1><<<ge2, 256, 0, stream>>>(slAB, dlAB, asAB, adAB, pbufAB,
                                       slBA, dlBA, asBA, adBA, pbufBA, E);
  gat_agg<1, true><<<aB, 256, 0, stream>>>(rpAB, slAB, pbufAB, hsAB, V(10), V(20), V(21), hB, nullptr, d_out, NA, flag, NB);
  gat_agg<1, true><<<aA, 256, 0, stream>>>(rpBA, slBA, pbufBA, hsBA, V(13), V(18), V(19), hA, nullptr, d_out, 0, flag, NA);
}